// Round 1
// 289.193 us; speedup vs baseline: 1.0164x; 1.0164x over previous
//
#include <hip/hip_runtime.h>

typedef __attribute__((ext_vector_type(8))) short bf16x8;
typedef __attribute__((ext_vector_type(4))) float f32x4;

#define D_DIM 256
#define NROW  8192

__device__ __forceinline__ unsigned short f2bf(float x) {
  unsigned int u = __float_as_uint(x);
  u += 0x7fffu + ((u >> 16) & 1u);   // round-to-nearest-even
  return (unsigned short)(u >> 16);
}

__device__ __forceinline__ void gload_lds16(const void* g, void* l) {
  __builtin_amdgcn_global_load_lds((__attribute__((address_space(1))) void*)g,
                                   (__attribute__((address_space(3))) void*)l,
                                   16, 0, 0);
}

// One wave per row (D=256 -> 4 floats/lane). fp32 softmax, bf16 output.
__global__ __launch_bounds__(256) void softmax_rows(const float* __restrict__ S,
                                                    unsigned short* __restrict__ P) {
  const int row  = blockIdx.x * 4 + (threadIdx.x >> 6);
  const int lane = threadIdx.x & 63;
  float4 v = ((const float4*)(S + row * D_DIM))[lane];
  float m = fmaxf(fmaxf(v.x, v.y), fmaxf(v.z, v.w));
#pragma unroll
  for (int off = 32; off > 0; off >>= 1) m = fmaxf(m, __shfl_xor(m, off));
  float e0 = __expf(v.x - m), e1 = __expf(v.y - m);
  float e2 = __expf(v.z - m), e3 = __expf(v.w - m);
  float s = e0 + e1 + e2 + e3;
#pragma unroll
  for (int off = 32; off > 0; off >>= 1) s += __shfl_xor(s, off);
  const float inv = 1.0f / s;
  ushort4 o;
  o.x = f2bf(e0 * inv); o.y = f2bf(e1 * inv);
  o.z = f2bf(e2 * inv); o.w = f2bf(e3 * inv);
  ((ushort4*)(P + row * D_DIM))[lane] = o;
}

__global__ __launch_bounds__(256) void cast_v(const float* __restrict__ V,
                                              unsigned short* __restrict__ Vb) {
  const int i = blockIdx.x * 256 + threadIdx.x;  // one float4 per thread
  float4 v = ((const float4*)V)[i];
  ushort4 o;
  o.x = f2bf(v.x); o.y = f2bf(v.y); o.z = f2bf(v.z); o.w = f2bf(v.w);
  ((ushort4*)Vb)[i] = o;
}

// ---- GEMM helpers -----------------------------------------------------------

// Stage one 128x64 bf16 tile pair (A,B) into LDS buffer at `la` (A) / la+8192 (B).
// LDS dest is linear in thread id (gload_lds constraint); the bank-swizzle is
// applied on the GLOBAL source column (ga/gb already carry the XOR'd column).
__device__ __forceinline__ void stage_tile(const unsigned short* ga,
                                           const unsigned short* gb,
                                           unsigned short* la, int ko) {
  gload_lds16(ga + ko,              la);
  gload_lds16(ga + 32 * D_DIM + ko, la + 2048);
  gload_lds16(ga + 64 * D_DIM + ko, la + 4096);
  gload_lds16(ga + 96 * D_DIM + ko, la + 6144);
  gload_lds16(gb + ko,              la + 8192);
  gload_lds16(gb + 32 * D_DIM + ko, la + 8192 + 2048);
  gload_lds16(gb + 64 * D_DIM + ko, la + 8192 + 4096);
  gload_lds16(gb + 96 * D_DIM + ko, la + 8192 + 6144);
}

// Compute one BK=64 tile: 2 k-subtiles x 16 MFMAs. Reads use the same XOR
// swizzle the staging applied on the source: col ^= (row&7)*8 (shorts).
__device__ __forceinline__ void compute_tile(const unsigned short* __restrict__ A_,
                                             const unsigned short* __restrict__ B_,
                                             int arow, int brow, int k16,
                                             f32x4 acc[4][4]) {
#pragma unroll
  for (int j = 0; j < 2; ++j) {
    bf16x8 af[4], bfr[4];
#pragma unroll
    for (int mi = 0; mi < 4; ++mi) {
      const int r = arow + mi * 16;
      af[mi] = *(const bf16x8*)&A_[r * 64 + ((j * 32 + k16) ^ ((r & 7) * 8))];
    }
#pragma unroll
    for (int ni = 0; ni < 4; ++ni) {
      const int r = brow + ni * 16;
      bfr[ni] = *(const bf16x8*)&B_[r * 64 + ((j * 32 + k16) ^ ((r & 7) * 8))];
    }
#pragma unroll
    for (int mi = 0; mi < 4; ++mi)
#pragma unroll
      for (int ni = 0; ni < 4; ++ni)
        acc[mi][ni] = __builtin_amdgcn_mfma_f32_16x16x32_bf16(af[mi], bfr[ni],
                                                              acc[mi][ni], 0, 0, 0);
  }
}

// NT GEMM: O[i,j] = sum_k P[i,k] * Vb[j,k].  128x128 tile, BK=64, double-
// buffered LDS (2-phase: issue next tile's loads BEFORE computing current,
// one vmcnt(0)+barrier per tile). 4 waves in 2x2, each wave 64x64.
__global__ __launch_bounds__(256) void gemm_bt(const unsigned short* __restrict__ P,
                                               const unsigned short* __restrict__ Vb,
                                               float* __restrict__ O) {
  // 64 KB LDS: buf0 {As[0,8192) Bs[8192,16384)}, buf1 {+16384}. Shorts.
  // Epilogue aliases the first 34816 B (after a full __syncthreads()).
  __shared__ unsigned short smem[32768];

  const int t    = threadIdx.x;
  const int lane = t & 63;
  const int wave = t >> 6;
  const int wm   = (wave & 1) * 64;
  const int wn   = (wave >> 1) * 64;

  // XCD stripe mapping: xcd = id%8 owns bm in [xcd*8, xcd*8+8), bm-fastest.
  // Resident window per XCD ~ 8 P-panels + 8 V-panels ~ 1 MB -> L2-resident.
  const int id  = blockIdx.x;
  const int xcd = id & 7;
  const int q   = id >> 3;
  const int bm  = xcd * 8 + (q & 7);
  const int bn  = q >> 3;

  f32x4 acc[4][4] = {};

  // Staging: thread t covers rows srow+{0,32,64,96}, 16B chunk (t&7) of the
  // 128 B row. Global column carries the inverse swizzle so that the linear
  // LDS write leaves data at LDS[row][col ^ (row&7)*8].
  const int srow = t >> 3;
  const int xg   = ((t & 7) * 8) ^ ((srow & 7) * 8);   // swizzled col (shorts)
  const unsigned short* ga = P  + (size_t)(bm * 128 + srow) * D_DIM + xg;
  const unsigned short* gb = Vb + (size_t)(bn * 128 + srow) * D_DIM + xg;
  unsigned short* l0 = smem + t * 8;                   // byte offset t*16

  // Fragment addressing: A[m=lane&15][k=(lane>>4)*8 + e]
  const int arow = wm + (lane & 15);
  const int brow = wn + (lane & 15);
  const int k16  = (lane >> 4) * 8;

  // ---- 2-phase double-buffered K loop (4 tiles of BK=64) ----
  stage_tile(ga, gb, l0, 0);
  asm volatile("s_waitcnt vmcnt(0)" ::: "memory");
  __builtin_amdgcn_s_barrier();
  __builtin_amdgcn_sched_barrier(0);

  stage_tile(ga, gb, l0 + 16384, 64);                  // prefetch tile 1
  compute_tile(smem, smem + 8192, arow, brow, k16, acc);
  asm volatile("s_waitcnt vmcnt(0)" ::: "memory");
  __builtin_amdgcn_s_barrier();
  __builtin_amdgcn_sched_barrier(0);

  stage_tile(ga, gb, l0, 128);                         // prefetch tile 2
  compute_tile(smem + 16384, smem + 24576, arow, brow, k16, acc);
  asm volatile("s_waitcnt vmcnt(0)" ::: "memory");
  __builtin_amdgcn_s_barrier();
  __builtin_amdgcn_sched_barrier(0);

  stage_tile(ga, gb, l0 + 16384, 192);                 // prefetch tile 3
  compute_tile(smem, smem + 8192, arow, brow, k16, acc);
  asm volatile("s_waitcnt vmcnt(0)" ::: "memory");
  __builtin_amdgcn_s_barrier();
  __builtin_amdgcn_sched_barrier(0);

  compute_tile(smem + 16384, smem + 24576, arow, brow, k16, acc);

  __syncthreads();   // full drain; epilogue reuses the LDS

  // ---- Epilogue: wave-local LDS transpose, then float4 coalesced stores ----
  // MFMA C/D layout: col = lane&15, row = (lane>>4)*4 + reg.
  // Per-wave buffer: 32 rows x 68 floats (pad +4 breaks bank aliasing).
  float* smf = (float*)smem;
  float* ep  = smf + wave * 2176;
  const int qrow = (lane >> 4) * 4;          // 0,4,8,12
  const int qcol = lane & 15;
  const size_t orow0 = (size_t)(bm * 128 + wm);
  const int    ocol0 = bn * 128 + wn + (lane & 15) * 4;

#pragma unroll
  for (int p = 0; p < 2; ++p) {              // two 32-row passes
#pragma unroll
    for (int mi2 = 0; mi2 < 2; ++mi2) {
      const int mi = p * 2 + mi2;
      const int r0 = mi2 * 16 + qrow;
#pragma unroll
      for (int ni = 0; ni < 4; ++ni)
#pragma unroll
        for (int r = 0; r < 4; ++r)
          ep[(r0 + r) * 68 + ni * 16 + qcol] = acc[mi][ni][r];
    }
    // wave-local: ds_write -> ds_read same region is wave-ordered (lgkmcnt)
#pragma unroll
    for (int qq = 0; qq < 8; ++qq) {
      const int rl = qq * 4 + (lane >> 4);   // 0..31 within pass
      float4 vv = *(const float4*)&ep[rl * 68 + (lane & 15) * 4];
      *(float4*)&O[(orow0 + p * 32 + rl) * NROW + ocol0] = vv;
    }
    if (p == 0) __syncthreads();             // cheap; keeps waves in lockstep
  }
}

extern "C" void kernel_launch(void* const* d_in, const int* in_sizes, int n_in,
                              void* d_out, int out_size, void* d_ws, size_t ws_size,
                              hipStream_t stream) {
  const float* S = (const float*)d_in[0];   // [8192, 256] fp32
  const float* V = (const float*)d_in[1];   // [8192, 256] fp32
  float* O = (float*)d_out;                 // [8192, 8192] fp32

  unsigned short* P  = (unsigned short*)d_ws;          // 4 MB bf16 softmax(S)
  unsigned short* Vb = P + (size_t)NROW * D_DIM;       // 4 MB bf16 V

  softmax_rows<<<NROW / 4, 256, 0, stream>>>(S, P);
  cast_v<<<(NROW * D_DIM / 4) / 256, 256, 0, stream>>>(V, Vb);
  gemm_bt<<<NROW / 128 * (NROW / 128), 256, 0, stream>>>(P, Vb, O);
}